// Round 7
// baseline (349.996 us; speedup 1.0000x reference)
//
#include <hip/hip_runtime.h>

// Causal depthwise conv1d: y[b,s,h] = sum_j x[b,s-3+j,h] * w[h,j], * mask[b,s]
// B=4, S=4096, H=2048, K=4, fp32.
//
// R9 post-mortem: vector-side issue rate hit 6.05 TB/s (= copy ceiling) but 3/4
// of reads were redundant halo re-reads. R3/R8 (1R+1W) never exceeded 3.2-3.4
// TB/s issue because the reg sliding-window lets the compiler serialize (VGPR=32
// every round). R10: 1R+1W global traffic at R9's issue rate via a 128KiB LDS
// ring: stage each tile once (global->reg->ds_write, issue pinned by
// sched_barrier(0), prefetch distance 2), taps read from LDS. Raw s_barrier +
// lgkmcnt(0) only (no vmcnt(0) drain). 256 persistent blocks = exactly 1/CU.
// Predict: kernel 78 -> 45-60us, hbm_gbps >= 4 TB/s, occupancy ~25% (by design).

constexpr int  B_   = 4;
constexpr int  S_   = 4096;
constexpr int  H_   = 2048;
constexpr int  H4   = H_ / 4;                 // 512 float4 per (b,s) row
constexpr long TOT4 = (long)B_ * S_ * H4;     // 8,388,608 float4
constexpr int  TPB  = 512;                    // 8 waves/block
constexpr int  TILE = 2048;                   // float4 per tile = 4 rows
constexpr int  RING = 8192;                   // float4 ring = 128 KiB = 4 tiles
constexpr int  NBLK = 256;                    // 1 block/CU (LDS forces placement)
constexpr int  NTIL = (int)(TOT4 / (long)TILE / NBLK);  // 16 tiles per block
constexpr int  SPAN = TILE * NTIL;            // 32768 float4 = 64 rows per block

typedef float f32x4 __attribute__((ext_vector_type(4)));

__device__ __forceinline__ void sfence() { __builtin_amdgcn_sched_barrier(0); }

__global__ __launch_bounds__(TPB, 2) void budgie_dwconv1d_kernel(
    const float* __restrict__ x,     // [B,S,H]
    const float* __restrict__ w,     // [H,K]
    const float* __restrict__ mask,  // [B,S]
    float* __restrict__ y)           // [B,S,H]
{
    // Ring invariant (mod 8192, offsets relative to tile base a):
    //   readers of tile k touch [-1536, +2048); ds_write(k+1) = [+2048, +4096);
    //   in-flight loads(k+2) land at [+4096, +6144) ≡ [-4096, -2048). All disjoint.
    __shared__ float4 ring[RING];                 // 128 KiB

    const int  t  = threadIdx.x;                  // == h4 for every element we touch
    const long a0 = (long)blockIdx.x * SPAN;      // span start (mult of 8192 -> ring pos 0)
    const int  s0 = (int)((a0 >> 9) & (S_ - 1));  // first row's s (multiple of 64)

    const float4* __restrict__ x4 = (const float4*)x;
    const float4* __restrict__ w4 = (const float4*)w;
    const float4* __restrict__ y4 = (const float4*)y;

    // Per-channel taps (h4 == t invariant): one float4 per channel.
    const float4 w0 = w4[t * 4 + 0];
    const float4 w1 = w4[t * 4 + 1];
    const float4 w2 = w4[t * 4 + 2];
    const float4 w3 = w4[t * 4 + 3];

    const float4 zero4 = make_float4(0.f, 0.f, 0.f, 0.f);

    // ---- Prologue: stage halo (3 rows) + tile 0; preload P = tile 1.
    if (s0 != 0) {                                // s0==0 -> taps zero-selected anyway
        #pragma unroll
        for (int j = 0; j < 3; ++j)
            ring[(RING - 1536) + j * 512 + t] = x4[a0 - 1536 + j * 512 + t];
    }
    #pragma unroll
    for (int j = 0; j < 4; ++j)
        ring[j * 512 + t] = x4[a0 + j * 512 + t];

    float4 P[4], Q[4];
    #pragma unroll
    for (int j = 0; j < 4; ++j) P[j] = x4[a0 + TILE + j * 512 + t];
    #pragma unroll
    for (int j = 0; j < 4; ++j) Q[j] = zero4;

    asm volatile("s_waitcnt lgkmcnt(0)" ::: "memory");
    sfence();
    __builtin_amdgcn_s_barrier();
    sfence();

    // ---- Main loop: 16 tiles.
    for (int k = 0; k < NTIL; ++k) {
        // (1) Issue loads for tile k+2 NOW; sched_barrier pins them above compute.
        if (k + 2 < NTIL) {
            const long an = a0 + (long)(k + 2) * TILE;
            #pragma unroll
            for (int j = 0; j < 4; ++j) Q[j] = x4[an + j * 512 + t];
        }
        sfence();

        // (2) Compute tile k from the ring.
        const int  rb = (k & 3) * TILE;           // ring base of tile k
        const long a  = a0 + (long)k * TILE;
        #pragma unroll
        for (int j = 0; j < 4; ++j) {
            const int  idx = rb + j * 512 + t;
            const long e   = a + j * 512 + t;     // global float4 index
            const int  row = (int)(e >> 9);       // b*S + s (block-uniform per j)
            const int  s   = row & (S_ - 1);

            const float4 x0v = ring[idx];
            float4 x1v = ring[(unsigned)(idx -  512) & (RING - 1)];
            float4 x2v = ring[(unsigned)(idx - 1024) & (RING - 1)];
            float4 x3v = ring[(unsigned)(idx - 1536) & (RING - 1)];
            x1v = (s >= 1) ? x1v : zero4;         // uniform selects (b-boundary rows)
            x2v = (s >= 2) ? x2v : zero4;
            x3v = (s >= 3) ? x3v : zero4;

            const int   row_u = __builtin_amdgcn_readfirstlane(row);
            const float m     = mask[row_u];      // uniform -> scalar load

            f32x4 o;
            o.x = fmaf(x3v.x, w0.x, fmaf(x2v.x, w0.y, fmaf(x1v.x, w0.z, x0v.x * w0.w)));
            o.y = fmaf(x3v.y, w1.x, fmaf(x2v.y, w1.y, fmaf(x1v.y, w1.z, x0v.y * w1.w)));
            o.z = fmaf(x3v.z, w2.x, fmaf(x2v.z, w2.y, fmaf(x1v.z, w2.z, x0v.z * w2.w)));
            o.w = fmaf(x3v.w, w3.x, fmaf(x2v.w, w3.y, fmaf(x1v.w, w3.z, x0v.w * w3.w)));
            o.x *= m; o.y *= m; o.z *= m; o.w *= m;

            __builtin_nontemporal_store(o, (f32x4*)(y4 + e));
        }

        // (3) Commit tile k+1 to the ring (loaded one iteration ago -> short wait).
        if (k + 1 < NTIL) {
            const int rb1 = ((k + 1) & 3) * TILE;
            #pragma unroll
            for (int j = 0; j < 4; ++j) ring[rb1 + j * 512 + t] = P[j];
        }
        #pragma unroll
        for (int j = 0; j < 4; ++j) P[j] = Q[j];  // rotate (static indices)

        // (4) ds_writes visible to all waves; do NOT drain vmcnt (loads/stores
        //     stay in flight across the barrier).
        asm volatile("s_waitcnt lgkmcnt(0)" ::: "memory");
        sfence();
        __builtin_amdgcn_s_barrier();
        sfence();
    }
}

extern "C" void kernel_launch(void* const* d_in, const int* in_sizes, int n_in,
                              void* d_out, int out_size, void* d_ws, size_t ws_size,
                              hipStream_t stream) {
    const float* x    = (const float*)d_in[0];   // hidden_states [B,S,H]
    const float* w    = (const float*)d_in[1];   // weight [H,K]
    const float* mask = (const float*)d_in[2];   // attention_mask_2d [B,S]
    float* y = (float*)d_out;

    budgie_dwconv1d_kernel<<<dim3(NBLK), TPB, 0, stream>>>(x, w, mask, y);
}

// Round 8
// 236.207 us; speedup vs baseline: 1.4817x; 1.4817x over previous
//
#include <hip/hip_runtime.h>

// Causal depthwise conv1d: y[b,s,h] = sum_j x[b,s-3+j,h] * w[h,j], * mask[b,s]
// B=4, S=4096, H=2048, K=4, fp32.
//
// Machine model after R9/R10: vector path sustains ~6 TB/s ONLY with independent
// loop iterations + continuous issue (R9: 6.05 TB/s, copy: 6.3). R3/R8 had ideal
// traffic but 3.5-4.1 TB/s issue (carried dep / convoy drain / block churn).
// R10's LDS ring: dead (3.6x write amplification, 194us).
// R11 = R8 traffic x R9 issue structure: persistent blocks, register double-
// buffered 8-row chunks. Per iter: issue next chunk's 11 independent row-loads,
// sched_barrier, consume current chunk (waits hit loads issued a whole iteration
// ago), rotate (static indices, full unroll -> renamed, no moves).
// 512 blocks x 4 chunks; step i covers exactly batch b=i; chunked XCD swizzle
// -> each XCD sweeps a contiguous 4MB slab, halo re-reads are neighbor-L2 hits.
// Predict: VGPR 100-128 (gate), dur 55-68us, BW>=3.5 TB/s, WRITE ~131MB.

constexpr int B_   = 4;
constexpr int S_   = 4096;
constexpr int H_   = 2048;
constexpr int H4   = H_ / 4;            // 512 float4 per row
constexpr int TPB  = 512;               // thread t == column h4
constexpr int ROWS = 8;                 // rows per chunk
constexpr int NCH  = B_ * S_ / ROWS;    // 2048 chunks
constexpr int NBLK = 512;               // persistent blocks (2 per CU)
constexpr int ITER = NCH / NBLK;        // 4 chunks per block
constexpr int NXCD = 8;

typedef float f32x4 __attribute__((ext_vector_type(4)));

struct Buf { float4 v[ROWS + 3]; };     // rows r0-3 .. r0+7 of this thread's column

__device__ __forceinline__ void load_chunk(Buf& d, int r0, int s0, int t,
                                           const float4* __restrict__ x4) {
    const long a = (long)r0 * H4 + t;
    if (s0 != 0) {                       // uniform branch; s0==0 only at b-starts
        #pragma unroll
        for (int j = 0; j < 3; ++j) d.v[j] = x4[a + (long)(j - 3) * H4];
    } else {
        const float4 z = make_float4(0.f, 0.f, 0.f, 0.f);
        #pragma unroll
        for (int j = 0; j < 3; ++j) d.v[j] = z;   // causal zero-pad, no OOB load
    }
    #pragma unroll
    for (int j = 0; j < ROWS; ++j) d.v[3 + j] = x4[a + (long)j * H4];
}

__device__ __forceinline__ void consume_chunk(const Buf& c, int r0, int t,
                                              const float4& w0, const float4& w1,
                                              const float4& w2, const float4& w3,
                                              const float* __restrict__ mask,
                                              f32x4* __restrict__ y4) {
    const long a   = (long)r0 * H4 + t;
    const int  r0u = __builtin_amdgcn_readfirstlane(r0);   // force s_load for mask
    #pragma unroll
    for (int tr = 0; tr < ROWS; ++tr) {
        const float4 x3 = c.v[tr + 0];   // x[s-3]
        const float4 x2 = c.v[tr + 1];   // x[s-2]
        const float4 x1 = c.v[tr + 2];   // x[s-1]
        const float4 x0 = c.v[tr + 3];   // x[s]
        const float  m  = mask[r0u + tr];

        f32x4 o;
        o.x = fmaf(x3.x, w0.x, fmaf(x2.x, w0.y, fmaf(x1.x, w0.z, x0.x * w0.w)));
        o.y = fmaf(x3.y, w1.x, fmaf(x2.y, w1.y, fmaf(x1.y, w1.z, x0.y * w1.w)));
        o.z = fmaf(x3.z, w2.x, fmaf(x2.z, w2.y, fmaf(x1.z, w2.z, x0.z * w2.w)));
        o.w = fmaf(x3.w, w3.x, fmaf(x2.w, w3.y, fmaf(x1.w, w3.z, x0.w * w3.w)));
        o.x *= m; o.y *= m; o.z *= m; o.w *= m;

        __builtin_nontemporal_store(o, y4 + a + (long)tr * H4);
    }
}

__global__ __launch_bounds__(TPB, 4) void budgie_dwconv1d_kernel(
    const float* __restrict__ x,     // [B,S,H]
    const float* __restrict__ w,     // [H,K]
    const float* __restrict__ mask,  // [B,S]
    float* __restrict__ y)           // [B,S,H]
{
    const int t = threadIdx.x;

    // Chunked XCD swizzle (bijective, 512 % 8 == 0): XCD k owns bswz [k*64,(k+1)*64)
    // -> per step, XCD k sweeps a contiguous 4MB slab; chunk halos are neighbor-L2.
    const int bswz = (blockIdx.x & (NXCD - 1)) * (NBLK / NXCD) + (blockIdx.x >> 3);

    const float4* __restrict__ x4 = (const float4*)x;
    const float4* __restrict__ w4 = (const float4*)w;
    f32x4* __restrict__ y4 = (f32x4*)y;

    // Per-channel taps (column t is loop-invariant): one float4 per channel.
    const float4 w0 = w4[t * 4 + 0];
    const float4 w1 = w4[t * 4 + 1];
    const float4 w2 = w4[t * 4 + 2];
    const float4 w3 = w4[t * 4 + 3];

    Buf A, Bv;

    // Prologue: chunk for step 0.
    {
        const int r0 = bswz * ROWS;
        load_chunk(A, r0, r0 & (S_ - 1), t, x4);
    }

    #pragma unroll
    for (int i = 0; i < ITER; ++i) {     // full unroll: A/Bv renamed, static idx
        const int r0 = (i * NBLK + bswz) * ROWS;

        // (1) Issue next chunk's 11 independent loads NOW (depth-1 prefetch).
        if (i + 1 < ITER) {
            const int r0n = ((i + 1) * NBLK + bswz) * ROWS;
            load_chunk(Bv, r0n, r0n & (S_ - 1), t, x4);
        }
        // (2) Pin the issue point: loads may not sink into the consume phase.
        __builtin_amdgcn_sched_barrier(0);

        // (3) Consume current chunk — its loads were issued a full iteration ago.
        consume_chunk(A, r0, t, w0, w1, w2, w3, mask, y4);

        // (4) Rotate (compile-time renamed away under full unroll).
        if (i + 1 < ITER) {
            #pragma unroll
            for (int j = 0; j < ROWS + 3; ++j) A.v[j] = Bv.v[j];
        }
    }
}

extern "C" void kernel_launch(void* const* d_in, const int* in_sizes, int n_in,
                              void* d_out, int out_size, void* d_ws, size_t ws_size,
                              hipStream_t stream) {
    const float* x    = (const float*)d_in[0];   // hidden_states [B,S,H]
    const float* w    = (const float*)d_in[1];   // weight [H,K]
    const float* mask = (const float*)d_in[2];   // attention_mask_2d [B,S]
    float* y = (float*)d_out;

    budgie_dwconv1d_kernel<<<dim3(NBLK), TPB, 0, stream>>>(x, w, mask, y);
}